// Round 7
// baseline (169.330 us; speedup 1.0000x reference)
//
#include <hip/hip_runtime.h>
#include <hip/hip_cooperative_groups.h>

namespace cg = cooperative_groups;

// B=64, D=256, M=100
//   k(b,i,j) = sum_m sign(f_i)sign(f_j)min(|f_i|,|f_j|) * exp(T)   [0.5 absorbed]
//   out = k - rowmean_i - rowmean_j (symmetric), triu-packed per batch.
// Single cooperative kernel: 1280 blocks (tile-pair x M-half), fdot2 inner loop,
// grid.sync(), then h=0 blocks combine + center + pack. No atomics, no memset.

#define NB 64
#define DD 256
#define MM 100
#define TILE 64
#define NUT 10                 // upper 64x64 tile-pairs of the 4x4 tile grid
#define TRI_PER_B 32896        // D*(D+1)/2
#define NTILE 640              // NB * NUT
#define NMH 50                 // M-half
#define NM2H 25                // fp16x2 m-pairs per half
#define TILE_F (TILE * TILE)

typedef unsigned int u32;
typedef _Float16 f16x2 __attribute__((ext_vector_type(2)));
typedef _Float16 f16x4 __attribute__((ext_vector_type(4)));

__device__ __forceinline__ void tile_coords(int t, int& ti, int& tj) {
    int a = (t >= 4) + (t >= 7) + (t >= 9);
    int s = (a * (9 - a)) >> 1;   // 0,4,7,9
    ti = a;
    tj = t - s + a;
}

// For row-group g, the 4 (ut, side) slots covering its row sums.
// byte = ut | (side<<5): g0:{0A,1A,2A,3A} g1:{4A,5A,6A,1B} g2:{7A,8A,2B,5B} g3:{9A,3B,6B,8B}
__device__ __forceinline__ u32 slot_enc(int g) {
    return g == 0 ? 0x03020100u : g == 1 ? 0x21060504u
         : g == 2 ? 0x25220807u : 0x28262309u;
}

__global__ void __launch_bounds__(256, 5)
k_fused(const float* __restrict__ f, const float* __restrict__ temp,
        float* __restrict__ part, _Float16* __restrict__ tiles,
        float* __restrict__ out) {
    __shared__ u32 As[NM2H][TILE];   // 6.4 KB
    __shared__ u32 Bs[NM2H][TILE];
    const int t = threadIdx.x;
    const int bid = blockIdx.x;       // 0..1279
    const int h = bid & 1;            // M-half
    const int bt = bid >> 1;          // tile id 0..639
    const int b = bt / NUT;
    const int ut = bt % NUT;
    int ti, tj;
    tile_coords(ut, ti, tj);
    const int i0 = ti * TILE, j0 = tj * TILE;
    const float* fb = f + (size_t)b * DD * MM + h * NMH;

    // Stage: f32 pairs -> packed fp16, layout [m2][row]. 2-way bank = free.
    for (int l = t; l < TILE * NM2H; l += 256) {   // 1600
        const int il = l & 63;
        const int m2 = l >> 6;
        float2 v = *reinterpret_cast<const float2*>(fb + (size_t)(i0 + il) * MM + m2 * 2);
        As[m2][il] = __builtin_bit_cast(u32, __builtin_amdgcn_cvt_pkrtz(v.x, v.y));
        float2 w = *reinterpret_cast<const float2*>(fb + (size_t)(j0 + il) * MM + m2 * 2);
        Bs[m2][il] = __builtin_bit_cast(u32, __builtin_amdgcn_cvt_pkrtz(w.x, w.y));
    }
    __syncthreads();

    const int tix = t & 15, tiy = t >> 4;
    float acc[4][4] = {};

    #pragma unroll 5
    for (int m2 = 0; m2 < NM2H; ++m2) {
        uint4 afu = *reinterpret_cast<const uint4*>(&As[m2][tix * 4]);
        uint4 bfu = *reinterpret_cast<const uint4*>(&Bs[m2][tiy * 4]);
        const u32 av[4] = {afu.x, afu.y, afu.z, afu.w};
        const u32 bv[4] = {bfu.x, bfu.y, bfu.z, bfu.w};
        u32 aab[4], aso[4], bab[4], bsg[4];
        #pragma unroll
        for (int q = 0; q < 4; ++q) {
            aab[q] = av[q] & 0x7fff7fffu;                 // |a|
            aso[q] = (av[q] & 0x80008000u) | 0x3c003c00u; // +-1.0 w/ a's sign
        }
        #pragma unroll
        for (int r = 0; r < 4; ++r) {
            bab[r] = bv[r] & 0x7fff7fffu;                 // |b|
            bsg[r] = bv[r] & 0x80008000u;                 // b's sign
        }
        #pragma unroll
        for (int q = 0; q < 4; ++q) {
            #pragma unroll
            for (int r = 0; r < 4; ++r) {
                u32 so = aso[q] ^ bsg[r];                 // +-1.0 product sign
                f16x2 mn = __builtin_elementwise_min(
                    __builtin_bit_cast(f16x2, aab[q]),
                    __builtin_bit_cast(f16x2, bab[r]));   // v_pk_min_f16
                acc[q][r] = __builtin_amdgcn_fdot2(
                    mn, __builtin_bit_cast(f16x2, so), acc[q][r], false);
            }
        }
    }

    // h=1: partial tile -> ws as f16 (h=0 keeps its half in registers)
    if (h == 1) {
        _Float16* tp = tiles + (size_t)bt * TILE_F;
        #pragma unroll
        for (int q = 0; q < 4; ++q) {
            f16x4 hv;
            hv.x = (_Float16)acc[q][0]; hv.y = (_Float16)acc[q][1];
            hv.z = (_Float16)acc[q][2]; hv.w = (_Float16)acc[q][3];
            *reinterpret_cast<f16x4*>(tp + (tix * 4 + q) * TILE + tiy * 4) = hv;
        }
    }

    // row/col partial sums -> part[bt][h][side][64]
    float ra[4], cb[4];
    #pragma unroll
    for (int q = 0; q < 4; ++q)
        ra[q] = (acc[q][0] + acc[q][1]) + (acc[q][2] + acc[q][3]);
    #pragma unroll
    for (int r = 0; r < 4; ++r)
        cb[r] = (acc[0][r] + acc[1][r]) + (acc[2][r] + acc[3][r]);

    __syncthreads();                       // reuse As/Bs as f32 scratch
    float* red  = reinterpret_cast<float*>(&As[0][0]);   // [16][64]
    float* red2 = reinterpret_cast<float*>(&Bs[0][0]);   // [16][64]
    #pragma unroll
    for (int q = 0; q < 4; ++q) red[tiy * 64 + tix * 4 + q] = ra[q];
    #pragma unroll
    for (int r = 0; r < 4; ++r) red2[tix * 64 + tiy * 4 + r] = cb[r];
    __syncthreads();

    const size_t pbase = (size_t)bt * 256 + (size_t)h * 128;
    if (t < TILE) {
        float s = 0.f;
        #pragma unroll
        for (int w = 0; w < 16; ++w) s += red[w * 64 + t];
        part[pbase + t] = s;                       // side 0 (rows i0..)
    } else if (t < 2 * TILE && ti != tj) {
        const int u = t - TILE;
        float s = 0.f;
        #pragma unroll
        for (int w = 0; w < 16; ++w) s += red2[w * 64 + u];
        part[pbase + 64 + u] = s;                  // side 1 (rows j0..)
    }

    // ---- grid-wide sync: all partials visible ----
    cg::this_grid().sync();
    if (h == 1) return;

    // combine the other half's tile
    const _Float16* tp = tiles + (size_t)bt * TILE_F;
    #pragma unroll
    for (int q = 0; q < 4; ++q) {
        f16x4 v = *reinterpret_cast<const f16x4*>(tp + (tix * 4 + q) * TILE + tiy * 4);
        acc[q][0] += (float)v.x; acc[q][1] += (float)v.y;
        acc[q][2] += (float)v.z; acc[q][3] += (float)v.w;
    }

    // reconstruct the 128 row sums this tile needs (8 slot-loads each)
    float* rows_sh = reinterpret_cast<float*>(&As[0][0]);   // 128 floats
    if (t < 128) {
        const int half = t >> 6, u = t & 63;
        const int g = half ? tj : ti;
        const u32 enc = slot_enc(g);
        float sum = 0.f;
        #pragma unroll
        for (int s = 0; s < 4; ++s) {
            const u32 byte = (enc >> (8 * s)) & 0xffu;
            const int ut_s = byte & 0x1f;
            const int side = byte >> 5;
            const size_t idx = (size_t)(b * NUT + ut_s) * 256 + side * 64 + u;
            sum += part[idx] + part[idx + 128];    // h=0 + h=1
        }
        rows_sh[t] = sum;
    }
    __syncthreads();

    const float scale = expf(temp[0]);   // 0.5 absorbed by sign-min identity
    const float inv_d = 1.0f / DD;
    const int cbase = (ti == tj) ? 0 : 64;
    float rloc[4], cloc[4];
    #pragma unroll
    for (int q = 0; q < 4; ++q) rloc[q] = rows_sh[tix * 4 + q];
    #pragma unroll
    for (int r = 0; r < 4; ++r) cloc[r] = rows_sh[cbase + tiy * 4 + r];

    float* ob = out + (size_t)b * TRI_PER_B;
    #pragma unroll
    for (int q = 0; q < 4; ++q) {
        const int i = i0 + tix * 4 + q;
        float v[4];
        #pragma unroll
        for (int r = 0; r < 4; ++r)
            v[r] = scale * (acc[q][r] - (rloc[q] + cloc[r]) * inv_d);
        const int j0e = j0 + tiy * 4;
        if (ti != tj) {
            const int off = (i * (2 * DD - i + 1)) / 2 + (j0e - i);
            *reinterpret_cast<float4*>(ob + off) = make_float4(v[0], v[1], v[2], v[3]);
        } else {
            #pragma unroll
            for (int r = 0; r < 4; ++r) {
                const int j = j0e + r;
                if (j >= i) {
                    const int off = (i * (2 * DD - i + 1)) / 2 + (j - i);
                    ob[off] = v[r];
                }
            }
        }
    }
}

extern "C" void kernel_launch(void* const* d_in, const int* in_sizes, int n_in,
                              void* d_out, int out_size, void* d_ws, size_t ws_size,
                              hipStream_t stream) {
    const float* f    = (const float*)d_in[0];
    const float* temp = (const float*)d_in[1];
    float* out  = (float*)d_out;
    float* part = (float*)d_ws;                           // 640*256 f32 = 655 KB
    _Float16* tiles = (_Float16*)(part + NTILE * 256);    // 640*4096 f16 = 5.25 MB

    void* args[] = {(void*)&f, (void*)&temp, (void*)&part, (void*)&tiles, (void*)&out};
    hipLaunchCooperativeKernel((const void*)k_fused, dim3(2 * NTILE), dim3(256),
                               args, 0, stream);
}

// Round 8
// 135.777 us; speedup vs baseline: 1.2471x; 1.2471x over previous
//
#include <hip/hip_runtime.h>

// B=64, D=256, M=100
//   k(b,i,j) = sum_m sign(f_i)sign(f_j)min(|f_i|,|f_j|) * exp(T)   [0.5 absorbed]
//   out = k - rowmean_i - rowmean_j (symmetric), triu-packed per batch.
// Single kernel + per-batch counter barrier (NO cg::grid.sync — 130us on MI355X).
// 1280 blocks (tile-pair x M-half), all co-resident by construction
// (launch_bounds(256,5): 5 blocks/CU * 256 CU = 1280; LDS 12.8KB*5=64KB ok).
// fdot2 packed-fp16 inner loop (3 VALU / pair / 2m).

#define NB 64
#define DD 256
#define MM 100
#define TILE 64
#define NUT 10                 // upper 64x64 tile-pairs of the 4x4 tile grid
#define TRI_PER_B 32896        // D*(D+1)/2
#define NTILE 640              // NB * NUT
#define NMH 50                 // M-half
#define NM2H 25                // fp16x2 m-pairs per half
#define TILE_F (TILE * TILE)
#define BLKS_PER_BATCH 20u     // 10 tiles * 2 halves

typedef unsigned int u32;
typedef _Float16 f16x2 __attribute__((ext_vector_type(2)));
typedef _Float16 f16x4 __attribute__((ext_vector_type(4)));

__device__ __forceinline__ void tile_coords(int t, int& ti, int& tj) {
    int a = (t >= 4) + (t >= 7) + (t >= 9);
    int s = (a * (9 - a)) >> 1;   // 0,4,7,9
    ti = a;
    tj = t - s + a;
}

// For row-group g, the 4 (ut, side) slots covering its row sums.
// byte = ut | (side<<5): g0:{0A,1A,2A,3A} g1:{4A,5A,6A,1B} g2:{7A,8A,2B,5B} g3:{9A,3B,6B,8B}
__device__ __forceinline__ u32 slot_enc(int g) {
    return g == 0 ? 0x03020100u : g == 1 ? 0x21060504u
         : g == 2 ? 0x25220807u : 0x28262309u;
}

extern "C" __global__ void __launch_bounds__(256, 5)
k_fused(const float* __restrict__ f, const float* __restrict__ temp,
        float* __restrict__ part, _Float16* __restrict__ tiles,
        u32* __restrict__ ctr, float* __restrict__ out) {
    __shared__ u32 As[NM2H][TILE];   // 6.4 KB
    __shared__ u32 Bs[NM2H][TILE];
    const int t = threadIdx.x;
    const int bid = blockIdx.x;       // 0..1279
    const int h = bid & 1;            // M-half
    const int bt = bid >> 1;          // tile id 0..639
    const int b = bt / NUT;
    const int ut = bt % NUT;
    int ti, tj;
    tile_coords(ut, ti, tj);
    const int i0 = ti * TILE, j0 = tj * TILE;
    const float* fb = f + (size_t)b * DD * MM + h * NMH;

    // Stage: f32 pairs -> packed fp16, layout [m2][row]. 2-way bank = free.
    for (int l = t; l < TILE * NM2H; l += 256) {   // 1600
        const int il = l & 63;
        const int m2 = l >> 6;
        float2 v = *reinterpret_cast<const float2*>(fb + (size_t)(i0 + il) * MM + m2 * 2);
        As[m2][il] = __builtin_bit_cast(u32, __builtin_amdgcn_cvt_pkrtz(v.x, v.y));
        float2 w = *reinterpret_cast<const float2*>(fb + (size_t)(j0 + il) * MM + m2 * 2);
        Bs[m2][il] = __builtin_bit_cast(u32, __builtin_amdgcn_cvt_pkrtz(w.x, w.y));
    }
    __syncthreads();

    const int tix = t & 15, tiy = t >> 4;
    float acc[4][4] = {};

    #pragma unroll 5
    for (int m2 = 0; m2 < NM2H; ++m2) {
        uint4 afu = *reinterpret_cast<const uint4*>(&As[m2][tix * 4]);
        uint4 bfu = *reinterpret_cast<const uint4*>(&Bs[m2][tiy * 4]);
        const u32 av[4] = {afu.x, afu.y, afu.z, afu.w};
        const u32 bv[4] = {bfu.x, bfu.y, bfu.z, bfu.w};
        u32 aab[4], aso[4], bab[4], bsg[4];
        #pragma unroll
        for (int q = 0; q < 4; ++q) {
            aab[q] = av[q] & 0x7fff7fffu;                 // |a|
            aso[q] = (av[q] & 0x80008000u) | 0x3c003c00u; // +-1.0 w/ a's sign
        }
        #pragma unroll
        for (int r = 0; r < 4; ++r) {
            bab[r] = bv[r] & 0x7fff7fffu;                 // |b|
            bsg[r] = bv[r] & 0x80008000u;                 // b's sign
        }
        #pragma unroll
        for (int q = 0; q < 4; ++q) {
            #pragma unroll
            for (int r = 0; r < 4; ++r) {
                u32 so = aso[q] ^ bsg[r];                 // +-1.0 product sign
                f16x2 mn = __builtin_elementwise_min(
                    __builtin_bit_cast(f16x2, aab[q]),
                    __builtin_bit_cast(f16x2, bab[r]));   // v_pk_min_f16
                acc[q][r] = __builtin_amdgcn_fdot2(
                    mn, __builtin_bit_cast(f16x2, so), acc[q][r], false);
            }
        }
    }

    // h=1: partial tile -> ws as f16 (h=0 keeps its half in registers)
    if (h == 1) {
        _Float16* tp = tiles + (size_t)bt * TILE_F;
        #pragma unroll
        for (int q = 0; q < 4; ++q) {
            f16x4 hv;
            hv.x = (_Float16)acc[q][0]; hv.y = (_Float16)acc[q][1];
            hv.z = (_Float16)acc[q][2]; hv.w = (_Float16)acc[q][3];
            *reinterpret_cast<f16x4*>(tp + (tix * 4 + q) * TILE + tiy * 4) = hv;
        }
    }

    // row/col partial sums -> part[bt][h][side][64]
    float ra[4], cb[4];
    #pragma unroll
    for (int q = 0; q < 4; ++q)
        ra[q] = (acc[q][0] + acc[q][1]) + (acc[q][2] + acc[q][3]);
    #pragma unroll
    for (int r = 0; r < 4; ++r)
        cb[r] = (acc[0][r] + acc[1][r]) + (acc[2][r] + acc[3][r]);

    __syncthreads();                       // reuse As/Bs as f32 scratch
    float* red  = reinterpret_cast<float*>(&As[0][0]);   // [16][64]
    float* red2 = reinterpret_cast<float*>(&Bs[0][0]);   // [16][64]
    #pragma unroll
    for (int q = 0; q < 4; ++q) red[tiy * 64 + tix * 4 + q] = ra[q];
    #pragma unroll
    for (int r = 0; r < 4; ++r) red2[tix * 64 + tiy * 4 + r] = cb[r];
    __syncthreads();

    const size_t pbase = (size_t)bt * 256 + (size_t)h * 128;
    if (t < TILE) {
        float s = 0.f;
        #pragma unroll
        for (int w = 0; w < 16; ++w) s += red[w * 64 + t];
        part[pbase + t] = s;                       // side 0 (rows i0..)
    } else if (t < 2 * TILE && ti != tj) {
        const int u = t - TILE;
        float s = 0.f;
        #pragma unroll
        for (int w = 0; w < 16; ++w) s += red2[w * 64 + u];
        part[pbase + 64 + u] = s;                  // side 1 (rows j0..)
    }

    // ---- per-batch arrival barrier ----
    __syncthreads();            // drains vmcnt(0): all block writes off the wave
    if (t == 0) {
        __threadfence();        // agent release: writes visible device-wide
        atomicAdd(&ctr[b], 1u);
    }
    if (h == 1) return;

    if (t == 0) {
        while (atomicAdd(&ctr[b], 0u) < BLKS_PER_BATCH)
            __builtin_amdgcn_s_sleep(2);
        __threadfence();        // agent acquire: invalidate stale cache lines
    }
    __syncthreads();

    // combine the other half's tile
    const _Float16* tp = tiles + (size_t)bt * TILE_F;
    #pragma unroll
    for (int q = 0; q < 4; ++q) {
        f16x4 v = *reinterpret_cast<const f16x4*>(tp + (tix * 4 + q) * TILE + tiy * 4);
        acc[q][0] += (float)v.x; acc[q][1] += (float)v.y;
        acc[q][2] += (float)v.z; acc[q][3] += (float)v.w;
    }

    // reconstruct the 128 row sums this tile needs (8 slot-loads each)
    float* rows_sh = reinterpret_cast<float*>(&As[0][0]);   // 128 floats
    if (t < 128) {
        const int half = t >> 6, u = t & 63;
        const int g = half ? tj : ti;
        const u32 enc = slot_enc(g);
        float sum = 0.f;
        #pragma unroll
        for (int s = 0; s < 4; ++s) {
            const u32 byte = (enc >> (8 * s)) & 0xffu;
            const int ut_s = byte & 0x1f;
            const int side = byte >> 5;
            const size_t idx = (size_t)(b * NUT + ut_s) * 256 + side * 64 + u;
            sum += part[idx] + part[idx + 128];    // h=0 + h=1
        }
        rows_sh[t] = sum;
    }
    __syncthreads();

    const float scale = expf(temp[0]);   // 0.5 absorbed by sign-min identity
    const float inv_d = 1.0f / DD;
    const int cbase = (ti == tj) ? 0 : 64;
    float rloc[4], cloc[4];
    #pragma unroll
    for (int q = 0; q < 4; ++q) rloc[q] = rows_sh[tix * 4 + q];
    #pragma unroll
    for (int r = 0; r < 4; ++r) cloc[r] = rows_sh[cbase + tiy * 4 + r];

    float* ob = out + (size_t)b * TRI_PER_B;
    #pragma unroll
    for (int q = 0; q < 4; ++q) {
        const int i = i0 + tix * 4 + q;
        float v[4];
        #pragma unroll
        for (int r = 0; r < 4; ++r)
            v[r] = scale * (acc[q][r] - (rloc[q] + cloc[r]) * inv_d);
        const int j0e = j0 + tiy * 4;
        if (ti != tj) {
            const int off = (i * (2 * DD - i + 1)) / 2 + (j0e - i);
            *reinterpret_cast<float4*>(ob + off) = make_float4(v[0], v[1], v[2], v[3]);
        } else {
            #pragma unroll
            for (int r = 0; r < 4; ++r) {
                const int j = j0e + r;
                if (j >= i) {
                    const int off = (i * (2 * DD - i + 1)) / 2 + (j - i);
                    ob[off] = v[r];
                }
            }
        }
    }
}

extern "C" void kernel_launch(void* const* d_in, const int* in_sizes, int n_in,
                              void* d_out, int out_size, void* d_ws, size_t ws_size,
                              hipStream_t stream) {
    const float* f    = (const float*)d_in[0];
    const float* temp = (const float*)d_in[1];
    float* out  = (float*)d_out;
    float* part = (float*)d_ws;                           // 640*256 f32 = 655 KB
    _Float16* tiles = (_Float16*)(part + NTILE * 256);    // 640*4096 f16 = 5.25 MB
    u32* ctr = (u32*)(tiles + (size_t)NTILE * TILE_F);    // 64 u32

    hipMemsetAsync(ctr, 0, NB * sizeof(u32), stream);     // ws is poisoned, not re-poisoned
    k_fused<<<2 * NTILE, 256, 0, stream>>>(f, temp, part, tiles, ctr, out);
}

// Round 9
// 35.137 us; speedup vs baseline: 4.8192x; 3.8642x over previous
//
#include <hip/hip_runtime.h>

// B=64, D=256, M=100
//   k(b,i,j) = sum_m sign(f_i)sign(f_j)min(|f_i|,|f_j|) * exp(T)   [0.5 absorbed]
//   out = k - rowmean_i - rowmean_j (symmetric), triu-packed per batch.
// Two kernels (barrier-in-kernel spills regs -> 24 VGPR -> 3x slower; rounds 7/8).
// Pass1: 640 blocks, full-M 64x64 tile, fdot2 packed-fp16 loop, f16 tile + f32
// row/col partials to ws (no atomics, no memset). Pass2: center + triu-pack.

#define NB 64
#define DD 256
#define MM 100
#define TILE 64
#define NUT 10                 // upper 64x64 tile-pairs of the 4x4 tile grid
#define TRI_PER_B 32896        // D*(D+1)/2
#define NTILE 640              // NB * NUT
#define NM2 50                 // fp16x2 m-pairs (full M)
#define TILE_F (TILE * TILE)

typedef unsigned int u32;
typedef _Float16 f16x2 __attribute__((ext_vector_type(2)));
typedef _Float16 f16x4 __attribute__((ext_vector_type(4)));

__device__ __forceinline__ void tile_coords(int t, int& ti, int& tj) {
    int a = (t >= 4) + (t >= 7) + (t >= 9);
    int s = (a * (9 - a)) >> 1;   // 0,4,7,9
    ti = a;
    tj = t - s + a;
}

// For row-group g, the 4 (ut, side) slots covering its row sums.
// byte = ut | (side<<5): g0:{0A,1A,2A,3A} g1:{4A,5A,6A,1B} g2:{7A,8A,2B,5B} g3:{9A,3B,6B,8B}
__device__ __forceinline__ u32 slot_enc(int g) {
    return g == 0 ? 0x03020100u : g == 1 ? 0x21060504u
         : g == 2 ? 0x25220807u : 0x28262309u;
}

// XCD-aware swizzle: XCD x processes 80 consecutive tiles = 8 whole batches
// (f[b] = 100 KB stays in one XCD's L2). 640 % 8 == 0 -> bijective.
__device__ __forceinline__ int swz_bt(int w) { return (w & 7) * 80 + (w >> 3); }

extern "C" __global__ void __launch_bounds__(256, 4)
k_partial(const float* __restrict__ f, float* __restrict__ part,
          _Float16* __restrict__ tiles) {
    __shared__ u32 As[NM2][TILE];   // 12.8 KB
    __shared__ u32 Bs[NM2][TILE];   // 25.6 KB total
    const int t = threadIdx.x;
    const int bt = swz_bt(blockIdx.x);   // 0..639
    const int b = bt / NUT;
    const int ut = bt % NUT;
    int ti, tj;
    tile_coords(ut, ti, tj);
    const int i0 = ti * TILE, j0 = tj * TILE;
    const float* fb = f + (size_t)b * DD * MM;

    // Stage full M: f32 float4 -> 2x packed fp16, layout [m2][row].
    // LDS writes: consecutive lanes -> consecutive rows -> conflict-free.
    for (int l = t; l < TILE * 25; l += 256) {   // 1600 float4 per matrix
        const int il = l & 63;
        const int mq = l >> 6;                   // 0..24
        float4 v = *reinterpret_cast<const float4*>(fb + (size_t)(i0 + il) * MM + mq * 4);
        As[2 * mq + 0][il] = __builtin_bit_cast(u32, __builtin_amdgcn_cvt_pkrtz(v.x, v.y));
        As[2 * mq + 1][il] = __builtin_bit_cast(u32, __builtin_amdgcn_cvt_pkrtz(v.z, v.w));
        float4 w = *reinterpret_cast<const float4*>(fb + (size_t)(j0 + il) * MM + mq * 4);
        Bs[2 * mq + 0][il] = __builtin_bit_cast(u32, __builtin_amdgcn_cvt_pkrtz(w.x, w.y));
        Bs[2 * mq + 1][il] = __builtin_bit_cast(u32, __builtin_amdgcn_cvt_pkrtz(w.z, w.w));
    }
    __syncthreads();

    const int tix = t & 15, tiy = t >> 4;
    float acc[4][4] = {};

    #pragma unroll 5
    for (int m2 = 0; m2 < NM2; ++m2) {
        uint4 afu = *reinterpret_cast<const uint4*>(&As[m2][tix * 4]);
        uint4 bfu = *reinterpret_cast<const uint4*>(&Bs[m2][tiy * 4]);
        const u32 av[4] = {afu.x, afu.y, afu.z, afu.w};
        const u32 bv[4] = {bfu.x, bfu.y, bfu.z, bfu.w};
        u32 aab[4], aso[4], bab[4], bsg[4];
        #pragma unroll
        for (int q = 0; q < 4; ++q) {
            aab[q] = av[q] & 0x7fff7fffu;                 // |a|
            aso[q] = (av[q] & 0x80008000u) | 0x3c003c00u; // +-1.0 w/ a's sign
        }
        #pragma unroll
        for (int r = 0; r < 4; ++r) {
            bab[r] = bv[r] & 0x7fff7fffu;                 // |b|
            bsg[r] = bv[r] & 0x80008000u;                 // b's sign
        }
        #pragma unroll
        for (int q = 0; q < 4; ++q) {
            #pragma unroll
            for (int r = 0; r < 4; ++r) {
                u32 so = aso[q] ^ bsg[r];                 // +-1.0 product sign
                f16x2 mn = __builtin_elementwise_min(
                    __builtin_bit_cast(f16x2, aab[q]),
                    __builtin_bit_cast(f16x2, bab[r]));   // v_pk_min_f16
                acc[q][r] = __builtin_amdgcn_fdot2(
                    mn, __builtin_bit_cast(f16x2, so), acc[q][r], false);
            }
        }
    }

    // complete tile -> ws as f16 [64][64]
    _Float16* tp = tiles + (size_t)bt * TILE_F;
    #pragma unroll
    for (int q = 0; q < 4; ++q) {
        f16x4 hv;
        hv.x = (_Float16)acc[q][0]; hv.y = (_Float16)acc[q][1];
        hv.z = (_Float16)acc[q][2]; hv.w = (_Float16)acc[q][3];
        *reinterpret_cast<f16x4*>(tp + (tix * 4 + q) * TILE + tiy * 4) = hv;
    }

    // row/col partial sums (f32) -> part[bt][side][64]
    float ra[4], cb[4];
    #pragma unroll
    for (int q = 0; q < 4; ++q)
        ra[q] = (acc[q][0] + acc[q][1]) + (acc[q][2] + acc[q][3]);
    #pragma unroll
    for (int r = 0; r < 4; ++r)
        cb[r] = (acc[0][r] + acc[1][r]) + (acc[2][r] + acc[3][r]);

    __syncthreads();                       // reuse As/Bs as f32 scratch
    float* red  = reinterpret_cast<float*>(&As[0][0]);   // [16][64]
    float* red2 = reinterpret_cast<float*>(&Bs[0][0]);   // [16][64]
    #pragma unroll
    for (int q = 0; q < 4; ++q) red[tiy * 64 + tix * 4 + q] = ra[q];
    #pragma unroll
    for (int r = 0; r < 4; ++r) red2[tix * 64 + tiy * 4 + r] = cb[r];
    __syncthreads();

    const size_t pbase = (size_t)bt * 128;
    if (t < TILE) {
        float s = 0.f;
        #pragma unroll
        for (int w = 0; w < 16; ++w) s += red[w * 64 + t];
        part[pbase + t] = s;                       // side 0 (rows i0..)
    } else if (t < 2 * TILE && ti != tj) {
        const int u = t - TILE;
        float s = 0.f;
        #pragma unroll
        for (int w = 0; w < 16; ++w) s += red2[w * 64 + u];
        part[pbase + 64 + u] = s;                  // side 1 (rows j0..)
    }
}

// Pass 2: reconstruct row sums from part, center, scale, triu-pack.
extern "C" __global__ void __launch_bounds__(256)
k_finalize(const float* __restrict__ part, const float* __restrict__ temp,
           const _Float16* __restrict__ tiles, float* __restrict__ out) {
    __shared__ float rows_sh[128];
    const int t = threadIdx.x;
    const int bt = swz_bt(blockIdx.x);   // 0..639
    const int b = bt / NUT;
    const int ut = bt % NUT;
    int ti, tj;
    tile_coords(ut, ti, tj);
    const int i0 = ti * TILE, j0 = tj * TILE;
    const int tix = t >> 4, tiy = t & 15;

    // reconstruct the 128 row sums this tile needs (4 slot-loads each)
    if (t < 128) {
        const int half = t >> 6, u = t & 63;
        const int g = half ? tj : ti;
        const u32 enc = slot_enc(g);
        float sum = 0.f;
        #pragma unroll
        for (int s = 0; s < 4; ++s) {
            const u32 byte = (enc >> (8 * s)) & 0xffu;
            const int ut_s = byte & 0x1f;
            const int side = byte >> 5;
            sum += part[(size_t)(b * NUT + ut_s) * 128 + side * 64 + u];
        }
        rows_sh[t] = sum;
    }

    const _Float16* tp = tiles + (size_t)bt * TILE_F;
    float acc[4][4];
    #pragma unroll
    for (int q = 0; q < 4; ++q) {
        f16x4 v = *reinterpret_cast<const f16x4*>(tp + (tix * 4 + q) * TILE + tiy * 4);
        acc[q][0] = (float)v.x; acc[q][1] = (float)v.y;
        acc[q][2] = (float)v.z; acc[q][3] = (float)v.w;
    }
    __syncthreads();

    const float scale = expf(temp[0]);   // 0.5 absorbed by sign-min identity
    const float inv_d = 1.0f / DD;
    const int cbase = (ti == tj) ? 0 : 64;
    float rloc[4], cloc[4];
    #pragma unroll
    for (int q = 0; q < 4; ++q) rloc[q] = rows_sh[tix * 4 + q];
    #pragma unroll
    for (int r = 0; r < 4; ++r) cloc[r] = rows_sh[cbase + tiy * 4 + r];

    float* ob = out + (size_t)b * TRI_PER_B;
    #pragma unroll
    for (int q = 0; q < 4; ++q) {
        const int i = i0 + tix * 4 + q;
        float v[4];
        #pragma unroll
        for (int r = 0; r < 4; ++r)
            v[r] = scale * (acc[q][r] - (rloc[q] + cloc[r]) * inv_d);
        const int j0e = j0 + tiy * 4;
        if (ti != tj) {
            const int off = (i * (2 * DD - i + 1)) / 2 + (j0e - i);
            *reinterpret_cast<float4*>(ob + off) = make_float4(v[0], v[1], v[2], v[3]);
        } else {
            #pragma unroll
            for (int r = 0; r < 4; ++r) {
                const int j = j0e + r;
                if (j >= i) {
                    const int off = (i * (2 * DD - i + 1)) / 2 + (j - i);
                    ob[off] = v[r];
                }
            }
        }
    }
}

extern "C" void kernel_launch(void* const* d_in, const int* in_sizes, int n_in,
                              void* d_out, int out_size, void* d_ws, size_t ws_size,
                              hipStream_t stream) {
    const float* f    = (const float*)d_in[0];
    const float* temp = (const float*)d_in[1];
    float* out  = (float*)d_out;
    float* part = (float*)d_ws;                           // 640*128 f32 = 328 KB
    _Float16* tiles = (_Float16*)(part + NTILE * 128);    // 640*4096 f16 = 5.25 MB

    k_partial<<<NTILE, 256, 0, stream>>>(f, part, tiles);
    k_finalize<<<NTILE, 256, 0, stream>>>(part, temp, tiles, out);
}